// Round 3
// baseline (3764.649 us; speedup 1.0000x reference)
//
#include <hip/hip_runtime.h>
#include <stdint.h>

#ifndef __has_builtin
#define __has_builtin(x) 0
#endif
#if __has_builtin(__builtin_amdgcn_fdot2)
#define HAVE_FDOT2 1
#else
#define HAVE_FDOT2 0
#endif

typedef float    f32x4 __attribute__((ext_vector_type(4)));
typedef _Float16 f16x2 __attribute__((ext_vector_type(2)));
typedef _Float16 f16x4 __attribute__((ext_vector_type(4)));
typedef _Float16 f16x8 __attribute__((ext_vector_type(8)));

#define NB 32
#define NL 2048
#define NM 256
#define NC 768            // 3 * NM packed projection columns
#define XS_SCALE 4096.0f  // int16 fixed point, range +-8, step 2.44e-4
#define XS_INV   2.44140625e-4f

__device__ __forceinline__ float dot2f(f16x2 a, f16x2 b, float c) {
#if HAVE_FDOT2
  return __builtin_amdgcn_fdot2(a, b, c, false);
#else
  float d;
  asm("v_dot2_f32_f16 %0, %1, %2, %3" : "=v"(d) : "v"(a), "v"(b), "v"(c));
  return d;
#endif
}

__device__ __forceinline__ float tanh_fast(float x) {
  x = fminf(fmaxf(x, -30.f), 30.f);
  float e = __expf(-2.f * x);
  return (1.f - e) / (1.f + e);
}
__device__ __forceinline__ float sigmoid_fast(float x) {
  x = fminf(fmaxf(x, -30.f), 30.f);
  return 1.f / (1.f + __expf(-x));
}

// ---------------- phase 1 ----------------
// xs[r][c] = round(4096 * sum_i u[r][i] * W(c)[c%256][i]) as int16.
// Split-f16 MFMA: u=uh+ul, W=wh+wl (f16 each); acc += uh*wh + uh*wl + ul*wh.
// Residual ~2^-22 relative -> projections are fp32-exact for our purposes.
__global__ __launch_bounds__(256) void proj_kernel(
    const float* __restrict__ u, const float* __restrict__ Wia,
    const float* __restrict__ Wic, const float* __restrict__ Wio,
    int16_t* __restrict__ xs)
{
  __shared__ _Float16 sAh[128][72];  // 72 = 64 + 8 pad, keeps 16B alignment
  __shared__ _Float16 sAl[128][72];
  __shared__ _Float16 sBh[128][72];
  __shared__ _Float16 sBl[128][72];
  const int tid = threadIdx.x;
  const int rb = blockIdx.x, cb = blockIdx.y;
  const float* W = (cb < 2) ? Wia : (cb < 4) ? Wic : Wio;
  const int wrow0 = (cb & 1) * 128;

  const int wave = tid >> 6, lane = tid & 63;
  const int wr = (wave >> 1) * 64, wc = (wave & 1) * 64;
  const int lrow = lane & 15, lk = (lane >> 4) * 8;

  f32x4 acc[4][4] = {};

  for (int kt = 0; kt < 4; ++kt) {
#pragma unroll
    for (int i = 0; i < 8; ++i) {
      int idx = tid + 256 * i;          // 0..2047 ; 16 float4 per 64-wide row
      int r = idx >> 4, c4 = idx & 15;
      f32x4 va = *reinterpret_cast<const f32x4*>(
          u + (size_t)(rb * 128 + r) * 256 + kt * 64 + c4 * 4);
      f16x4 hh, hl;
#pragma unroll
      for (int q = 0; q < 4; ++q) {
        _Float16 hi = (_Float16)va[q];
        hh[q] = hi;
        hl[q] = (_Float16)(va[q] - (float)hi);
      }
      *reinterpret_cast<f16x4*>(&sAh[r][c4 * 4]) = hh;
      *reinterpret_cast<f16x4*>(&sAl[r][c4 * 4]) = hl;
      f32x4 vb = *reinterpret_cast<const f32x4*>(
          W + (size_t)(wrow0 + r) * 256 + kt * 64 + c4 * 4);
      f16x4 gh, gl;
#pragma unroll
      for (int q = 0; q < 4; ++q) {
        _Float16 hi = (_Float16)vb[q];
        gh[q] = hi;
        gl[q] = (_Float16)(vb[q] - (float)hi);
      }
      *reinterpret_cast<f16x4*>(&sBh[r][c4 * 4]) = gh;
      *reinterpret_cast<f16x4*>(&sBl[r][c4 * 4]) = gl;
    }
    __syncthreads();
#pragma unroll
    for (int kk = 0; kk < 2; ++kk) {
      const int k0 = kk * 32 + lk;
      f16x8 afh[4], afl[4], bfh[4], bfl[4];
#pragma unroll
      for (int i = 0; i < 4; ++i) {
        afh[i] = *reinterpret_cast<const f16x8*>(&sAh[wr + i * 16 + lrow][k0]);
        afl[i] = *reinterpret_cast<const f16x8*>(&sAl[wr + i * 16 + lrow][k0]);
      }
#pragma unroll
      for (int j = 0; j < 4; ++j) {
        bfh[j] = *reinterpret_cast<const f16x8*>(&sBh[wc + j * 16 + lrow][k0]);
        bfl[j] = *reinterpret_cast<const f16x8*>(&sBl[wc + j * 16 + lrow][k0]);
      }
#pragma unroll
      for (int i = 0; i < 4; ++i)
#pragma unroll
        for (int j = 0; j < 4; ++j) {
          acc[i][j] = __builtin_amdgcn_mfma_f32_16x16x32_f16(afl[i], bfh[j], acc[i][j], 0, 0, 0);
          acc[i][j] = __builtin_amdgcn_mfma_f32_16x16x32_f16(afh[i], bfl[j], acc[i][j], 0, 0, 0);
          acc[i][j] = __builtin_amdgcn_mfma_f32_16x16x32_f16(afh[i], bfh[j], acc[i][j], 0, 0, 0);
        }
    }
    __syncthreads();
  }

  // C/D layout: col = lane&15, row = (lane>>4)*4 + q
  const size_t row0 = (size_t)rb * 128 + wr + (lane >> 4) * 4;
  const int col0 = cb * 128 + wc + (lane & 15);
#pragma unroll
  for (int i = 0; i < 4; ++i)
#pragma unroll
    for (int j = 0; j < 4; ++j)
#pragma unroll
      for (int q = 0; q < 4; ++q) {
        float v = acc[i][j][q] * XS_SCALE;
        v = fminf(fmaxf(v, -32767.f), 32767.f);
        xs[(row0 + i * 16 + q) * NC + (col0 + j * 16)] = (int16_t)__float2int_rn(v);
      }
}

// ---------------- phase 2 ----------------
// One workgroup per batch (32 wgs). Thread m owns row m of W_ha and W_hc
// (f16-packed, 256 VGPRs), h[m] fp32 in-register, h broadcast via LDS f16
// double buffer. One barrier per step. 4 accumulators per gate for fdot2 ILP.
__global__ __launch_bounds__(256, 1) void rec_kernel(
    const float* __restrict__ Wha, const float* __restrict__ Whc,
    const int16_t* __restrict__ xs, float* __restrict__ out)
{
  __shared__ __align__(16) _Float16 hbuf[2][256];
  const int m = threadIdx.x;
  const int b = blockIdx.x;

  f16x2 wa[128], wcr[128];
#pragma unroll
  for (int i = 0; i < 64; ++i) {
    f32x4 va = *reinterpret_cast<const f32x4*>(Wha + (size_t)m * 256 + i * 4);
    f16x2 t0; t0.x = (_Float16)va.x; t0.y = (_Float16)va.y;
    f16x2 t1; t1.x = (_Float16)va.z; t1.y = (_Float16)va.w;
    wa[2 * i] = t0; wa[2 * i + 1] = t1;
    f32x4 vc = *reinterpret_cast<const f32x4*>(Whc + (size_t)m * 256 + i * 4);
    f16x2 s0; s0.x = (_Float16)vc.x; s0.y = (_Float16)vc.y;
    f16x2 s1; s1.x = (_Float16)vc.z; s1.y = (_Float16)vc.w;
    wcr[2 * i] = s0; wcr[2 * i + 1] = s1;
  }

  float h = 0.f;
  hbuf[0][m] = (_Float16)0.f;
  hbuf[1][m] = (_Float16)0.f;
  __syncthreads();

  const int16_t* xrow = xs + (size_t)b * NL * NC;
  float xa = (float)xrow[m] * XS_INV;
  float xc = (float)xrow[256 + m] * XS_INV;
  float xo = (float)xrow[512 + m] * XS_INV;
  float* outb = out + (size_t)b * NL * NM;

  for (int l = 0; l < NL; ++l) {
    // prefetch next step's projections (consumed next iteration)
    const int lp = (l + 1 < NL) ? (l + 1) : (NL - 1);
    const int16_t* xr = xrow + (size_t)lp * NC;
    int16_t ra = xr[m], rc = xr[256 + m], ro = xr[512 + m];

    float aa[4] = {0.f, 0.f, 0.f, 0.f};
    float ac[4] = {0.f, 0.f, 0.f, 0.f};
    const f16x2* hp = reinterpret_cast<const f16x2*>(hbuf[l & 1]);
#pragma unroll
    for (int kk = 0; kk < 128; ++kk) {
      f16x2 hk = hp[kk];  // broadcast read, merges to ds_read_b128
      aa[kk & 3] = dot2f(hk, wa[kk], aa[kk & 3]);
      ac[kk & 3] = dot2f(hk, wcr[kk], ac[kk & 3]);
    }
    float sa = (aa[0] + aa[1]) + (aa[2] + aa[3]);
    float sc = (ac[0] + ac[1]) + (ac[2] + ac[3]);

    float a = 1.f + tanh_fast(xa + sa);
    float c = sigmoid_fast(xc + sc);
    float hn = c * h + (1.f - c) * tanh_fast(xo + a * h);
    h = hn;
    outb[(size_t)l * NM + m] = hn;
    hbuf[(l + 1) & 1][m] = (_Float16)hn;
    xa = (float)ra * XS_INV; xc = (float)rc * XS_INV; xo = (float)ro * XS_INV;
    __syncthreads();
  }
  out[(size_t)NB * NL * NM + (size_t)b * NM + m] = h;
}

extern "C" void kernel_launch(void* const* d_in, const int* in_sizes, int n_in,
                              void* d_out, int out_size, void* d_ws, size_t ws_size,
                              hipStream_t stream) {
  (void)in_sizes; (void)n_in; (void)out_size; (void)ws_size;
  const float* u   = (const float*)d_in[0];
  const float* Wia = (const float*)d_in[1];
  const float* Wha = (const float*)d_in[2];
  const float* Wic = (const float*)d_in[3];
  const float* Whc = (const float*)d_in[4];
  const float* Wio = (const float*)d_in[5];
  float* out = (float*)d_out;
  int16_t* xs = (int16_t*)d_ws;  // [65536][768] int16 = 96 MB

  proj_kernel<<<dim3(512, 6), 256, 0, stream>>>(u, Wia, Wic, Wio, xs);
  rec_kernel<<<NB, 256, 0, stream>>>(Wha, Whc, xs, out);
}

// Round 5
// 2863.689 us; speedup vs baseline: 1.3146x; 1.3146x over previous
//
#include <hip/hip_runtime.h>
#include <stdint.h>

#ifndef __has_builtin
#define __has_builtin(x) 0
#endif
#if __has_builtin(__builtin_amdgcn_fdot2)
#define HAVE_FDOT2 1
#else
#define HAVE_FDOT2 0
#endif

typedef float    f32x4 __attribute__((ext_vector_type(4)));
typedef _Float16 f16x2 __attribute__((ext_vector_type(2)));
typedef _Float16 f16x4 __attribute__((ext_vector_type(4)));
typedef _Float16 f16x8 __attribute__((ext_vector_type(8)));

#define NB 32
#define NL 2048
#define NM 256
#define NC 768            // 3 * NM packed projection columns
#define XS_SCALE 4096.0f  // int16 fixed point, range +-8, step 2.44e-4
#define XS_INV   2.44140625e-4f

__device__ __forceinline__ float dot2f(f16x2 a, f16x2 b, float c) {
#if HAVE_FDOT2
  return __builtin_amdgcn_fdot2(a, b, c, false);
#else
  float d;
  asm("v_dot2_f32_f16 %0, %1, %2, %3" : "=v"(d) : "v"(a), "v"(b), "v"(c));
  return d;
#endif
}

__device__ __forceinline__ float tanh_fast(float x) {
  x = fminf(fmaxf(x, -30.f), 30.f);
  float e = __expf(-2.f * x);
  return (1.f - e) / (1.f + e);
}
__device__ __forceinline__ float sigmoid_fast(float x) {
  x = fminf(fmaxf(x, -30.f), 30.f);
  return 1.f / (1.f + __expf(-x));
}

// ---------------- phase 1 (round-3 proven version, verbatim) ----------------
// xs[r][c] = round(4096 * sum_i u[r][i] * W(c)[c%256][i]) as int16.
// Split-f16 MFMA: u=uh+ul, W=wh+wl; acc += ul*wh + uh*wl + uh*wh.
__global__ __launch_bounds__(256) void proj_kernel(
    const float* __restrict__ u, const float* __restrict__ Wia,
    const float* __restrict__ Wic, const float* __restrict__ Wio,
    int16_t* __restrict__ xs)
{
  __shared__ _Float16 sAh[128][72];  // 72 = 64 + 8 pad, keeps 16B alignment
  __shared__ _Float16 sAl[128][72];
  __shared__ _Float16 sBh[128][72];
  __shared__ _Float16 sBl[128][72];
  const int tid = threadIdx.x;
  const int rb = blockIdx.x, cb = blockIdx.y;
  const float* W = (cb < 2) ? Wia : (cb < 4) ? Wic : Wio;
  const int wrow0 = (cb & 1) * 128;

  const int wave = tid >> 6, lane = tid & 63;
  const int wr = (wave >> 1) * 64, wc = (wave & 1) * 64;
  const int lrow = lane & 15, lk = (lane >> 4) * 8;

  f32x4 acc[4][4] = {};

  for (int kt = 0; kt < 4; ++kt) {
#pragma unroll
    for (int i = 0; i < 8; ++i) {
      int idx = tid + 256 * i;          // 0..2047 ; 16 float4 per 64-wide row
      int r = idx >> 4, c4 = idx & 15;
      f32x4 va = *reinterpret_cast<const f32x4*>(
          u + (size_t)(rb * 128 + r) * 256 + kt * 64 + c4 * 4);
      f16x4 hh, hl;
#pragma unroll
      for (int q = 0; q < 4; ++q) {
        _Float16 hi = (_Float16)va[q];
        hh[q] = hi;
        hl[q] = (_Float16)(va[q] - (float)hi);
      }
      *reinterpret_cast<f16x4*>(&sAh[r][c4 * 4]) = hh;
      *reinterpret_cast<f16x4*>(&sAl[r][c4 * 4]) = hl;
      f32x4 vb = *reinterpret_cast<const f32x4*>(
          W + (size_t)(wrow0 + r) * 256 + kt * 64 + c4 * 4);
      f16x4 gh, gl;
#pragma unroll
      for (int q = 0; q < 4; ++q) {
        _Float16 hi = (_Float16)vb[q];
        gh[q] = hi;
        gl[q] = (_Float16)(vb[q] - (float)hi);
      }
      *reinterpret_cast<f16x4*>(&sBh[r][c4 * 4]) = gh;
      *reinterpret_cast<f16x4*>(&sBl[r][c4 * 4]) = gl;
    }
    __syncthreads();
#pragma unroll
    for (int kk = 0; kk < 2; ++kk) {
      const int k0 = kk * 32 + lk;
      f16x8 afh[4], afl[4], bfh[4], bfl[4];
#pragma unroll
      for (int i = 0; i < 4; ++i) {
        afh[i] = *reinterpret_cast<const f16x8*>(&sAh[wr + i * 16 + lrow][k0]);
        afl[i] = *reinterpret_cast<const f16x8*>(&sAl[wr + i * 16 + lrow][k0]);
      }
#pragma unroll
      for (int j = 0; j < 4; ++j) {
        bfh[j] = *reinterpret_cast<const f16x8*>(&sBh[wc + j * 16 + lrow][k0]);
        bfl[j] = *reinterpret_cast<const f16x8*>(&sBl[wc + j * 16 + lrow][k0]);
      }
#pragma unroll
      for (int i = 0; i < 4; ++i)
#pragma unroll
        for (int j = 0; j < 4; ++j) {
          acc[i][j] = __builtin_amdgcn_mfma_f32_16x16x32_f16(afl[i], bfh[j], acc[i][j], 0, 0, 0);
          acc[i][j] = __builtin_amdgcn_mfma_f32_16x16x32_f16(afh[i], bfl[j], acc[i][j], 0, 0, 0);
          acc[i][j] = __builtin_amdgcn_mfma_f32_16x16x32_f16(afh[i], bfh[j], acc[i][j], 0, 0, 0);
        }
    }
    __syncthreads();
  }

  // C/D layout: col = lane&15, row = (lane>>4)*4 + q
  const size_t row0 = (size_t)rb * 128 + wr + (lane >> 4) * 4;
  const int col0 = cb * 128 + wc + (lane & 15);
#pragma unroll
  for (int i = 0; i < 4; ++i)
#pragma unroll
    for (int j = 0; j < 4; ++j)
#pragma unroll
      for (int q = 0; q < 4; ++q) {
        float v = acc[i][j][q] * XS_SCALE;
        v = fminf(fmaxf(v, -32767.f), 32767.f);
        xs[(row0 + i * 16 + q) * NC + (col0 + j * 16)] = (int16_t)__float2int_rn(v);
      }
}

// ---------------- phase 2 ----------------
// 1024 threads/wg, one wg per batch. Thread t: m = t>>2 (0..255 — FULL range,
// round-4 bug was m = t>>3 covering only half), r = t&3, gate g = r>>1
// (0: W_ha, 1: W_hc), k-half ks = r&1 (128 k-values).
// Per thread: 64 VGPRs of f16 weights (one gate, half row), static indexing.
// Quad reduction: shfl_xor(1) sums k-halves, shfl_xor(2) exchanges gates.
// h: f16 double-buffered LDS, halves at 272B stride (disjoint-bank b128
// broadcast reads). One barrier per step. 16 waves -> 4/SIMD TLP.
__global__ __launch_bounds__(1024, 1) void rec_kernel(
    const float* __restrict__ Wha, const float* __restrict__ Whc,
    const int16_t* __restrict__ xs, float* __restrict__ out)
{
  __shared__ __align__(16) _Float16 hbuf[2][2][136];  // 136 f16 = 272B stride
  const int t = threadIdx.x;
  const int m = t >> 2;
  const int r = t & 3;
  const int g = r >> 1;
  const int ks = r & 1;
  const int b = blockIdx.x;

  const float* Wg = g ? Whc : Wha;
  f16x2 w[64];
#pragma unroll
  for (int j = 0; j < 32; ++j) {
    f32x4 v = *reinterpret_cast<const f32x4*>(Wg + (size_t)m * 256 + ks * 128 + j * 4);
    f16x2 p0; p0.x = (_Float16)v.x; p0.y = (_Float16)v.y;
    f16x2 p1; p1.x = (_Float16)v.z; p1.y = (_Float16)v.w;
    w[2 * j] = p0; w[2 * j + 1] = p1;
  }

  for (int idx = t; idx < 2 * 2 * 136; idx += 1024)
    reinterpret_cast<_Float16*>(hbuf)[idx] = (_Float16)0.f;
  __syncthreads();

  const int16_t* xrow = xs + (size_t)b * NL * NC;
  float* outb = out + (size_t)b * NL * NM;

  // prefetch pipeline, depth 2 (int16 kept raw until use)
  int pa0 = xrow[m],      pc0 = xrow[NM + m],      po0 = xrow[2 * NM + m];
  int pa1 = xrow[NC + m], pc1 = xrow[NC + NM + m], po1 = xrow[NC + 2 * NM + m];

  float h = 0.f;

#pragma unroll 2
  for (int l = 0; l < NL; ++l) {
    int na = 0, ncc = 0, no = 0;
    if (l + 2 < NL) {
      const int16_t* xr = xrow + (size_t)(l + 2) * NC;
      na = xr[m]; ncc = xr[NM + m]; no = xr[2 * NM + m];
    }

    const _Float16* hs = &hbuf[l & 1][ks][0];
    float a0 = 0.f, a1 = 0.f, a2 = 0.f, a3 = 0.f;
#pragma unroll
    for (int i = 0; i < 16; ++i) {
      f16x8 hv = *reinterpret_cast<const f16x8*>(hs + 8 * i);  // ds_read_b128
      f16x2 h0; h0.x = hv[0]; h0.y = hv[1];
      f16x2 h1; h1.x = hv[2]; h1.y = hv[3];
      f16x2 h2; h2.x = hv[4]; h2.y = hv[5];
      f16x2 h3; h3.x = hv[6]; h3.y = hv[7];
      a0 = dot2f(h0, w[4 * i + 0], a0);
      a1 = dot2f(h1, w[4 * i + 1], a1);
      a2 = dot2f(h2, w[4 * i + 2], a2);
      a3 = dot2f(h3, w[4 * i + 3], a3);
    }
    float acc = (a0 + a1) + (a2 + a3);
    acc += __shfl_xor(acc, 1);         // sum the two k-halves (same gate)
    float other = __shfl_xor(acc, 2);  // the other gate's full sum
    float sa = g ? other : acc;
    float sc = g ? acc : other;

    float xa = (float)pa0 * XS_INV;
    float xc = (float)pc0 * XS_INV;
    float xo = (float)po0 * XS_INV;
    float a = 1.f + tanh_fast(xa + sa);
    float c = sigmoid_fast(xc + sc);
    float hn = c * h + (1.f - c) * tanh_fast(xo + a * h);
    h = hn;
    if (r == 0) {
      outb[(size_t)l * NM + m] = hn;
      hbuf[(l + 1) & 1][m >> 7][m & 127] = (_Float16)hn;
    }
    pa0 = pa1; pc0 = pc1; po0 = po1;
    pa1 = na;  pc1 = ncc; po1 = no;
    __syncthreads();
  }
  if (r == 0) out[(size_t)NB * NL * NM + (size_t)b * NM + m] = h;
}

extern "C" void kernel_launch(void* const* d_in, const int* in_sizes, int n_in,
                              void* d_out, int out_size, void* d_ws, size_t ws_size,
                              hipStream_t stream) {
  (void)in_sizes; (void)n_in; (void)out_size; (void)ws_size;
  const float* u   = (const float*)d_in[0];
  const float* Wia = (const float*)d_in[1];
  const float* Wha = (const float*)d_in[2];
  const float* Wic = (const float*)d_in[3];
  const float* Whc = (const float*)d_in[4];
  const float* Wio = (const float*)d_in[5];
  float* out = (float*)d_out;
  int16_t* xs = (int16_t*)d_ws;  // [65536][768] int16 = 96 MB

  proj_kernel<<<dim3(512, 6), 256, 0, stream>>>(u, Wia, Wic, Wio, xs);
  rec_kernel<<<NB, 1024, 0, stream>>>(Wha, Whc, xs, out);
}